// Round 9
// baseline (326.635 us; speedup 1.0000x reference)
//
#include <hip/hip_runtime.h>

#define NCLS 10

typedef __attribute__((ext_vector_type(8))) short short8;
typedef __attribute__((ext_vector_type(4))) float f32x4;

__device__ __forceinline__ float bf2f(ushort u) {
    return __uint_as_float(((unsigned int)u) << 16);
}
__device__ __forceinline__ ushort f2bf(float f) {
    unsigned int u = __float_as_uint(f);
    u = (u + 0x7FFFu + ((u >> 16) & 1u)) >> 16;
    return (ushort)u;
}
__device__ __forceinline__ float tanh_fast(float v) {
    float t = __expf(2.f * v);
    return (t - 1.f) / (t + 1.f);
}
__device__ __forceinline__ void gll16(const void* g, void* s) {
    __builtin_amdgcn_global_load_lds(
        (const __attribute__((address_space(1))) void*)g,
        (__attribute__((address_space(3))) void*)s, 16, 0, 0);
}

// ---------------------------------------------------------------------------
// exp tile v2: E[j][k] = bf16(exp(W[k][j])) for a 64-j stripe, full K=256;
// rcp_row[j] = 1/colsum. exp fused into load phase (LDS holds bf16),
// double-buffered chunks so HBM loads overlap the transpose/store phase.
// ---------------------------------------------------------------------------
__device__ void exp_tile(const float* __restrict__ Wb, ushort* __restrict__ Eb,
                         float* __restrict__ rcp_row, const int j0)
{
    __shared__ ushort sT[2][64][72];
    __shared__ float sC[4][64];
    const int tid = threadIdx.x;
    const int kk = tid >> 4;            // load: k row group
    const int jj = (tid & 15) * 4;      // load: 4 j's
    const int lj = tid >> 2;            // store: j column
    const int kq = tid & 3;             // store: k 16-group
    float csum = 0.f;

    auto load = [&](int buf, int c) {
        #pragma unroll
        for (int p = 0; p < 4; ++p) {
            const int row = p * 16 + kk;
            const float4 wv = *(const float4*)&Wb[(size_t)(c * 64 + row) * 256 + j0 + jj];
            ushort4 o;
            o.x = f2bf(__expf(wv.x)); o.y = f2bf(__expf(wv.y));
            o.z = f2bf(__expf(wv.z)); o.w = f2bf(__expf(wv.w));
            *(ushort4*)&sT[buf][row][jj] = o;
        }
    };

    load(0, 0);
    __syncthreads();
    for (int c = 0; c < 4; ++c) {
        const int buf = c & 1;
        if (c < 3) load(buf ^ 1, c + 1);
        ushort pk[16];
        #pragma unroll
        for (int t = 0; t < 16; ++t) {
            const ushort u = sT[buf][kq * 16 + t][lj];
            pk[t] = u;
            csum += bf2f(u);
        }
        short8 v0, v1;
        #pragma unroll
        for (int e2 = 0; e2 < 8; ++e2) { v0[e2] = (short)pk[e2]; v1[e2] = (short)pk[8 + e2]; }
        ushort* dst = Eb + (size_t)(j0 + lj) * 256 + c * 64 + kq * 16;
        *(short8*)dst = v0;
        *(short8*)(dst + 8) = v1;
        __syncthreads();
    }
    sC[kq][lj] = csum;
    __syncthreads();
    if (tid < 64)
        rcp_row[j0 + tid] = 1.f / (sC[0][tid] + sC[1][tid] + sC[2][tid] + sC[3][tid]);
}

// prep1: blocks [0,1024) = E0 + Rcp0; blocks [1024,1536) = H0 = tanh(x*Win),
// one block per (b, k-half): x row staged coalesced, Win rows L2-resident.
__global__ __launch_bounds__(256)
void prep1_kernel(const float* __restrict__ W0, const float* __restrict__ x,
                  const float* __restrict__ Win, ushort* __restrict__ E0,
                  float* __restrict__ Rcp0, ushort* __restrict__ H0)
{
    const int bid = blockIdx.x;
    if (bid < 1024) {
        const int ia = bid >> 2, jt = bid & 3;
        exp_tile(W0 + (size_t)ia * 65536, E0 + ((size_t)ia << 16),
                 Rcp0 + (size_t)ia * 256, jt * 64);
    } else {
        __shared__ float sXr[256];
        const int hb = bid - 1024;          // 0..511
        const int b  = hb >> 1;
        const int kh = (hb & 1) * 128;
        const int tid = threadIdx.x;
        sXr[tid] = x[(size_t)b * 256 + tid];
        __syncthreads();
        const int k  = kh + (tid & 63) * 2;
        const int dw = tid >> 6;
        for (int d0 = 0; d0 < 256; d0 += 4) {
            const int d = d0 + dw;
            const float2 wv = *(const float2*)&Win[(size_t)d * 256 + k];
            const float xb = sXr[d];
            const unsigned int u0 = f2bf(tanh_fast(xb * wv.x));
            const unsigned int u1 = f2bf(tanh_fast(xb * wv.y));
            *(unsigned int*)&H0[((size_t)b * 256 + d) * 256 + k] = u0 | (u1 << 16);
        }
    }
}

// prep2: E1..E7 (+Rcp rows 256..) — 1016 blocks
__global__ __launch_bounds__(256)
void prep2_kernel(const float* __restrict__ W1, const float* __restrict__ W2,
                  const float* __restrict__ W3, const float* __restrict__ W4,
                  const float* __restrict__ W5, const float* __restrict__ W6,
                  const float* __restrict__ W7,
                  ushort* __restrict__ Ebase, float* __restrict__ RcpBase)
{
    int rem = blockIdx.x;
    int lvl = 1, n2 = 128;
    while (rem >= n2 * 4 && lvl < 7) { rem -= n2 * 4; n2 >>= 1; ++lvl; }
    const int jt = rem & 3;
    const int ia = rem >> 2;
    const float* W;
    switch (lvl) {
        case 1: W = W1; break; case 2: W = W2; break; case 3: W = W3; break;
        case 4: W = W4; break; case 5: W = W5; break; case 6: W = W6; break;
        default: W = W7; break;
    }
    size_t eoff = 0; int rrow = 256;
    for (int m = 1; m < lvl; ++m) { eoff += ((size_t)(256 >> m)) << 16; rrow += (256 >> m); }
    exp_tile(W + (size_t)ia * 65536,
             Ebase + eoff + ((size_t)ia << 16),
             RcpBase + (size_t)(rrow + ia) * 256, jt * 64);
}

// ---------------------------------------------------------------------------
// Level GEMM (unchanged from R8, proven): tile BM x 64, BK=32, both a in
// block; 1-D grid bid = s*n + i -> all blocks of pair i on the same XCD.
// ---------------------------------------------------------------------------
template<int BM, int WR, int WC, int LB>
__global__ __launch_bounds__(256, LB)
void level_kernel(const ushort* __restrict__ H, const ushort* __restrict__ E,
                  const float* __restrict__ Rcp, ushort* __restrict__ Hout,
                  const int n, const int lg)
{
    constexpr int MF = BM / (16 * WR);
    constexpr int NF = 64 / (16 * WC);
    constexpr int NBH = 256 / BM;
    constexpr int AUNITS = 2 * BM / 16;
    constexpr int UITER = (AUNITS + 3) / 4;

    __shared__ __align__(16) char sA[2][2][BM * 64];
    __shared__ __align__(16) char sB[2][2][64 * 64];

    const int tid = threadIdx.x;
    const int bid = blockIdx.x;
    const int i   = bid & (n - 1);
    const int s   = bid >> lg;
    const int bh  = s % NBH;
    const int jt  = s / NBH;
    const int b0  = bh * BM;
    const int j0  = jt * 64;
    const int np  = 2 * n;

    const int l   = tid & 63;
    const int l15 = l & 15;
    const int g   = l >> 4;
    const int w   = tid >> 6;
    const int wm  = w / WC;
    const int wn  = w % WC;

    f32x4 acc[2][MF][NF];
    #pragma unroll
    for (int a2 = 0; a2 < 2; ++a2)
        #pragma unroll
        for (int mf = 0; mf < MF; ++mf)
            #pragma unroll
            for (int nf = 0; nf < NF; ++nf)
                acc[a2][mf][nf] = (f32x4){0.f, 0.f, 0.f, 0.f};

    auto stage = [&](int buf, int k0) {
        #pragma unroll
        for (int uu = 0; uu < UITER; ++uu) {
            const int u = w + uu * 4;
            if (u < AUNITS) {
                const int ua  = u / (BM / 16);
                const int r16 = (u % (BM / 16)) * 16;
                const int row = r16 + (l >> 2);
                const int c   = l & 3;
                const ushort* src = H
                    + ((size_t)(b0 + row) * np + (2 * i + ua)) * 256
                    + k0 + ((c ^ ((row >> 1) & 3)) << 3);
                gll16(src, &sA[ua][buf][r16 * 64]);
            }
        }
        #pragma unroll
        for (int vv = 0; vv < 2; ++vv) {
            const int v    = w + vv * 4;
            const int ea   = v >> 2;
            const int jr16 = (v & 3) * 16;
            const int jr   = jr16 + (l >> 2);
            const int c    = l & 3;
            const ushort* src = E + ((size_t)(2 * i + ea) << 16)
                + (size_t)(j0 + jr) * 256
                + k0 + ((c ^ ((jr >> 1) & 3)) << 3);
            gll16(src, &sB[ea][buf][jr16 * 64]);
        }
    };

    stage(0, 0);
    __syncthreads();

    for (int t = 0; t < 8; ++t) {
        const int buf = t & 1;
        if (t < 7) stage(buf ^ 1, (t + 1) * 32);

        short8 afr[2][MF];
        short8 bfr[2][NF];
        #pragma unroll
        for (int a2 = 0; a2 < 2; ++a2) {
            #pragma unroll
            for (int nf = 0; nf < NF; ++nf) {
                const int jr = wn * (NF * 16) + nf * 16 + l15;
                bfr[a2][nf] = *(const short8*)&sB[a2][buf][jr * 64 + ((g ^ ((jr >> 1) & 3)) << 4)];
            }
            #pragma unroll
            for (int mf = 0; mf < MF; ++mf) {
                const int row = wm * (MF * 16) + mf * 16 + l15;
                afr[a2][mf] = *(const short8*)&sA[a2][buf][row * 64 + ((g ^ ((row >> 1) & 3)) << 4)];
            }
        }
        #pragma unroll
        for (int a2 = 0; a2 < 2; ++a2)
            #pragma unroll
            for (int mf = 0; mf < MF; ++mf)
                #pragma unroll
                for (int nf = 0; nf < NF; ++nf)
                    acc[a2][mf][nf] = __builtin_amdgcn_mfma_f32_16x16x32_bf16(
                        afr[a2][mf], bfr[a2][nf], acc[a2][mf][nf], 0, 0, 0);
        __syncthreads();
    }

    float rc[2][NF];
    #pragma unroll
    for (int a2 = 0; a2 < 2; ++a2)
        #pragma unroll
        for (int nf = 0; nf < NF; ++nf)
            rc[a2][nf] = Rcp[(size_t)(2 * i + a2) * 256 + j0 + wn * (NF * 16) + nf * 16 + l15];

    #pragma unroll
    for (int mf = 0; mf < MF; ++mf)
        #pragma unroll
        for (int nf = 0; nf < NF; ++nf) {
            const int j = j0 + wn * (NF * 16) + nf * 16 + l15;
            #pragma unroll
            for (int r = 0; r < 4; ++r) {
                const int b = b0 + wm * (MF * 16) + mf * 16 + g * 4 + r;
                const float v0 = acc[0][mf][nf][r] * rc[0][nf];
                const float v1 = acc[1][mf][nf][r] * rc[1][nf];
                Hout[((size_t)b * n + i) * 256 + j] = f2bf(v0 * v1);
            }
        }
}

// ---------------------------------------------------------------------------
// Fused tail: L5 (np=8) -> L6 (np=4) -> L7 (np=2) -> head, per 16-row
// b-stripe, entirely in one block. E/Rcp read from global (L2-resident).
// LDS A-tiles use 16B-slot XOR swizzle: slot ^= (row & 7), applied on the
// pre-swizzled gll16 source, on scalar writes, and on b128 reads.
// ---------------------------------------------------------------------------
__global__ __launch_bounds__(256, 1)
void tail_kernel(const ushort* __restrict__ H5,   // (256, 8, 256) bf16
                 const ushort* __restrict__ E5, const ushort* __restrict__ E6,
                 const ushort* __restrict__ E7,
                 const float* __restrict__ R5, const float* __restrict__ R6,
                 const float* __restrict__ R7,
                 const float* __restrict__ Wout, float* __restrict__ out)
{
    __shared__ __align__(16) ushort sP[16 * 2048];   // H5; later H7 (front 16KB)
    __shared__ __align__(16) ushort sQ[16 * 1024];   // H6; later root (front 8KB)
    __shared__ float sEW[256][12];
    __shared__ float sDen[16];

    const int tid = threadIdx.x;
    const int b0  = blockIdx.x * 16;
    const int l   = tid & 63;
    const int l15 = l & 15;
    const int g   = l >> 4;
    const int w   = tid >> 6;

    if (tid < 16) sDen[tid] = 0.f;

    // stage H5 stripe: row = it, chunk = tid; pre-swizzled source + linear LDS
    for (int it = 0; it < 16; ++it) {
        const ushort* src = H5 + (size_t)(b0 + it) * 2048 + ((tid ^ (it & 7)) << 3);
        gll16(src, &sP[it * 2048 + w * 512]);
    }

    // head weights: e[k][c] + column sums
    float e[NCLS];
    #pragma unroll
    for (int c = 0; c < NCLS; ++c) {
        e[c] = __expf(Wout[(size_t)tid * NCLS + c]);
        sEW[tid][c] = e[c];
    }
    __syncthreads();   // sDen init + sP + sEW visible
    #pragma unroll
    for (int c = 0; c < NCLS; ++c) {
        float v = e[c];
        for (int off = 32; off > 0; off >>= 1) v += __shfl_down(v, off);
        if ((tid & 63) == 0) atomicAdd(&sDen[c], v);
    }

    auto level = [&](const ushort* src, int np_in, ushort* dst,
                     const ushort* El, const float* Rl) {
        const int pairs  = np_in >> 1;
        const int rl_in  = np_in * 256;
        const int rl_out = pairs * 256;
        const int j0w    = w * 64;
        for (int i = 0; i < pairs; ++i) {
            f32x4 acc[2][4];
            #pragma unroll
            for (int a = 0; a < 2; ++a)
                #pragma unroll
                for (int nf = 0; nf < 4; ++nf) acc[a][nf] = (f32x4){0.f,0.f,0.f,0.f};
            for (int t = 0; t < 8; ++t) {
                #pragma unroll
                for (int a = 0; a < 2; ++a) {
                    const int kidx = (2 * i + a) * 256 + t * 32 + g * 8;
                    const int slot = kidx >> 3;
                    const short8 afr = *(const short8*)&src[l15 * rl_in + ((slot ^ (l15 & 7)) << 3)];
                    #pragma unroll
                    for (int nf = 0; nf < 4; ++nf) {
                        const int j = j0w + nf * 16 + l15;
                        const short8 bfr = *(const short8*)&El[((size_t)(2 * i + a) << 16)
                                                               + (size_t)j * 256 + t * 32 + g * 8];
                        acc[a][nf] = __builtin_amdgcn_mfma_f32_16x16x32_bf16(
                            afr, bfr, acc[a][nf], 0, 0, 0);
                    }
                }
            }
            #pragma unroll
            for (int nf = 0; nf < 4; ++nf) {
                const int j = j0w + nf * 16 + l15;
                const float r0 = Rl[(2 * i + 0) * 256 + j];
                const float r1 = Rl[(2 * i + 1) * 256 + j];
                #pragma unroll
                for (int r = 0; r < 4; ++r) {
                    const int row  = g * 4 + r;
                    const float v  = (acc[0][nf][r] * r0) * (acc[1][nf][r] * r1);
                    const int oidx = i * 256 + j;
                    const int oslot = oidx >> 3;
                    dst[row * rl_out + ((oslot ^ (row & 7)) << 3) + (oidx & 7)] = f2bf(v);
                }
            }
        }
        __syncthreads();
    };

    level(sP, 8, sQ, E5, R5);   // H6 -> sQ (rowlen 1024)
    level(sQ, 4, sP, E6, R6);   // H7 -> sP front (rowlen 512)
    level(sP, 2, sQ, E7, R7);   // root -> sQ front (rowlen 256)

    // head
    const int ty = tid >> 4, tx = tid & 15;
    if (tx < NCLS) {
        float s = 0.f;
        for (int k = 0; k < 256; ++k) {
            const int slot = k >> 3;
            const ushort u = sQ[ty * 256 + ((slot ^ (ty & 7)) << 3) + (k & 7)];
            s += bf2f(u) * sEW[k][tx];
        }
        out[(size_t)(b0 + ty) * NCLS + tx] = s / sDen[tx];
    }
}

extern "C" void kernel_launch(void* const* d_in, const int* in_sizes, int n_in,
                              void* d_out, int out_size, void* d_ws, size_t ws_size,
                              hipStream_t stream)
{
    const float* x    = (const float*)d_in[0];
    const float* Win  = (const float*)d_in[1];
    const float* Wl[8];
    for (int lv = 0; lv < 8; ++lv) Wl[lv] = (const float*)d_in[2 + lv];
    const float* Wout = (const float*)d_in[10];
    float* out = (float*)d_out;

    char* wsb = (char*)d_ws;
    // Layout: A [0,32Mi): E0, then H2/H4 (A0) + H3/H5 (A1)
    //         C [32Mi,48Mi): H1
    //         B [48Mi,80Mi): H0, then E1..E7
    //         RC [80Mi, +522240)
    ushort* A0 = (ushort*)wsb;
    ushort* A1 = (ushort*)(wsb + 16777216);
    ushort* C  = (ushort*)(wsb + 33554432);
    ushort* B  = (ushort*)(wsb + 50331648);
    float*  RC = (float*)(wsb + 83886080);

    // E offsets (64Ki-ushort matrices) for levels 1..7 within the E region
    static const size_t ecum[8] = {0, 0, 128, 192, 224, 240, 248, 252};

    prep1_kernel<<<dim3(1536), 256, 0, stream>>>(Wl[0], x, Win, A0, RC, B);
    level_kernel<128, 2, 2, 3><<<dim3(8 * 128), 256, 0, stream>>>(
        B, A0, RC, C, 128, 7);
    prep2_kernel<<<dim3(1016), 256, 0, stream>>>(
        Wl[1], Wl[2], Wl[3], Wl[4], Wl[5], Wl[6], Wl[7], B, RC);

    level_kernel<64, 2, 2, 4><<<dim3(16 * 64), 256, 0, stream>>>(
        C, B + (ecum[1] << 16), RC + (256 + ecum[1]) * 256, A0, 64, 6);
    level_kernel<64, 2, 2, 4><<<dim3(16 * 32), 256, 0, stream>>>(
        A0, B + (ecum[2] << 16), RC + (256 + ecum[2]) * 256, A1, 32, 5);
    level_kernel<32, 2, 2, 4><<<dim3(32 * 16), 256, 0, stream>>>(
        A1, B + (ecum[3] << 16), RC + (256 + ecum[3]) * 256, A0, 16, 4);
    level_kernel<32, 2, 2, 4><<<dim3(32 * 8), 256, 0, stream>>>(
        A0, B + (ecum[4] << 16), RC + (256 + ecum[4]) * 256, A1, 8, 3);

    tail_kernel<<<dim3(16), 256, 0, stream>>>(
        A1,
        B + (ecum[5] << 16), B + (ecum[6] << 16), B + (ecum[7] << 16),
        RC + (256 + ecum[5]) * 256, RC + (256 + ecum[6]) * 256,
        RC + (256 + ecum[7]) * 256,
        Wout, out);
}